// Round 2
// baseline (423.303 us; speedup 1.0000x reference)
//
#include <hip/hip_runtime.h>
#include <hip/hip_bf16.h>
#include <stdint.h>

// Problem constants (fixed by the reference)
#define BB    16384
#define LL    4
#define IS    1024
#define HS    512
#define NOPS  3
#define M_TOT (BB*LL)        // 65536 rows
#define BM    128            // rows per block
#define BK    32             // K per step
#define NBLK  (M_TOT/BM)     // 512 blocks
#define KSTEPS (IS/BK)       // 32

typedef float  f32x4  __attribute__((ext_vector_type(4)));
typedef short  bf16x8 __attribute__((ext_vector_type(8)));
typedef unsigned short ushort_t;

__device__ __forceinline__ ushort_t f2bf(float f) {
  union { float f; uint32_t u; } v; v.f = f;
  uint32_t r = (v.u + 0x7FFFu + ((v.u >> 16) & 1u)) >> 16;  // RNE
  return (ushort_t)r;
}

__device__ __forceinline__ float tanh_fast(float x) {
  // tanh(x) = 1 - 2/(e^{2x}+1); exact limits at +-inf, monotone, ~1e-6 rel err
  float e = __expf(2.0f * x);
  return 1.0f - 2.0f * __builtin_amdgcn_rcpf(e + 1.0f);
}

// ---------------------------------------------------------------------------
// Prep: W1 [K=1024][N=512] fp32  ->  ws_b bf16, tiled per k-step as
// [kt][n][slot'][8] with slot' = slot ^ ((n>>1)&3)  (XOR bank swizzle),
// so the main kernel's LINEAR global_load_lds lands data where the swizzled
// ds_read_b128 pattern expects it.
// ---------------------------------------------------------------------------
__global__ __launch_bounds__(256) void prep_w1(const float* __restrict__ W1,
                                               ushort_t* __restrict__ wsb) {
  int g    = blockIdx.x * 256 + threadIdx.x;   // 65536 threads total
  int n    = g & (HS - 1);
  int slot = (g >> 9) & 3;
  int kt   = g >> 11;
  int sp   = slot ^ ((n >> 1) & 3);
  bf16x8 u;
#pragma unroll
  for (int j = 0; j < 8; ++j) {
    float f = W1[(size_t)(kt * BK + slot * 8 + j) * HS + n];
    u[j] = (short)f2bf(f);
  }
  *reinterpret_cast<bf16x8*>(&wsb[((size_t)(kt * HS + n) * 4 + sp) * 8]) = u;
}

// ---------------------------------------------------------------------------
// Main fused kernel: per block, 128 rows x full N=512.
//   h = tanh(X @ W1 + b1);  out = h @ W2 + b2   (epilogue fused, h never
//   touches global memory).
// ---------------------------------------------------------------------------
__global__ __launch_bounds__(512) void fused_main(
    const float* __restrict__ wenc, const float* __restrict__ rep_tab,
    const float* __restrict__ b1,   const float* __restrict__ W2,
    const float* __restrict__ b2,   const int* __restrict__ wn,
    const int* __restrict__ wc,     const ushort_t* __restrict__ wsb,
    float* __restrict__ out) {
  __shared__ __attribute__((aligned(16))) ushort_t As[2][BM * BK];  // 16 KB
  __shared__ __attribute__((aligned(16))) ushort_t Bs[2][HS * BK];  // 64 KB

  const int t    = threadIdx.x;
  const int lane = t & 63;
  const int wid  = t >> 6;
  const int wm   = wid >> 2;        // 0..1  (M half)
  const int wnq  = wid & 3;         // 0..3  (N quarter)
  const int lr   = lane & 15;
  const int lq   = lane >> 4;
  const int bid  = blockIdx.x;

  // ---- per-thread staging identity: this thread stages the SAME row/slot
  //      every k-step: row = t>>2, 8 floats at slot = t&3.
  const int srow = t >> 2;                    // 0..127
  const int sslot = t & 3;                    // 0..3
  const int grow = bid * BM + srow;           // global row in [0, 65536)
  const int b_  = grow >> 2;
  const int l_  = grow & 3;
  int c0 = wc[b_ * 4 + 0], c1 = wc[b_ * 4 + 1], c2 = wc[b_ * 4 + 2], c3 = wc[b_ * 4 + 3];
  int me = (l_ == 0) ? c0 : ((l_ == 1) ? c1 : ((l_ == 2) ? c2 : c3));
  int rep = 0;
  if (l_ > 0) rep += (c0 == me);
  if (l_ > 1) rep += (c1 == me);
  if (l_ > 2) rep += (c2 == me);
  const int code = (l_ < wn[b_]) ? rep : -1;  // -1 invalid row, 0 no-add, 1..3 add repeat[code]
  const float* aptr = wenc + (size_t)grow * IS + sslot * 8;
  const float* rptr = rep_tab + (size_t)rep * IS + sslot * 8;
  const int awoff = srow * BK + ((sslot ^ ((srow >> 1) & 3)) * 8);  // ushort units

  // ---- fragment read offsets (loop-invariant; swizzled)
  int aoff[4], boff[8];
#pragma unroll
  for (int mi = 0; mi < 4; ++mi) {
    int r = wm * 64 + mi * 16 + lr;
    aoff[mi] = r * BK + ((lq ^ ((r >> 1) & 3)) * 8);
  }
#pragma unroll
  for (int ni = 0; ni < 8; ++ni) {
    int n = wnq * 128 + ni * 16 + lr;
    boff[ni] = n * BK + ((lq ^ ((n >> 1) & 3)) * 8);
  }

  f32x4 acc[4][8];
#pragma unroll
  for (int mi = 0; mi < 4; ++mi)
#pragma unroll
    for (int ni = 0; ni < 8; ++ni) acc[mi][ni] = (f32x4){0.f, 0.f, 0.f, 0.f};

  // ---- staging helpers
  auto stageB = [&](int buf, int kt) {
    const ushort_t* src = wsb + (size_t)kt * (HS * BK);
#pragma unroll
    for (int i = 0; i < 4; ++i) {
      __builtin_amdgcn_global_load_lds(
          (const __attribute__((address_space(1))) void*)(src + i * 4096 + t * 8),
          (__attribute__((address_space(3))) void*)(&Bs[buf][i * 4096 + t * 8]),
          16, 0, 0);
    }
  };
  auto loadA = [&](int kt, float4& v0, float4& v1) {
    if (code >= 0) {
      const float4* p = reinterpret_cast<const float4*>(aptr + kt * BK);
      v0 = p[0]; v1 = p[1];
      if (code > 0) {
        const float4* q = reinterpret_cast<const float4*>(rptr + kt * BK);
        float4 r0 = q[0], r1 = q[1];
        v0.x += r0.x; v0.y += r0.y; v0.z += r0.z; v0.w += r0.w;
        v1.x += r1.x; v1.y += r1.y; v1.z += r1.z; v1.w += r1.w;
      }
    } else {
      v0 = make_float4(0.f, 0.f, 0.f, 0.f);
      v1 = make_float4(0.f, 0.f, 0.f, 0.f);
    }
  };
  auto writeA = [&](int buf, const float4& v0, const float4& v1) {
    bf16x8 u;
    u[0] = (short)f2bf(v0.x); u[1] = (short)f2bf(v0.y);
    u[2] = (short)f2bf(v0.z); u[3] = (short)f2bf(v0.w);
    u[4] = (short)f2bf(v1.x); u[5] = (short)f2bf(v1.y);
    u[6] = (short)f2bf(v1.z); u[7] = (short)f2bf(v1.w);
    *reinterpret_cast<bf16x8*>(&As[buf][awoff]) = u;
  };
  auto compute = [&](int buf) {
    bf16x8 af[4], bfr[8];
#pragma unroll
    for (int mi = 0; mi < 4; ++mi)
      af[mi] = *reinterpret_cast<const bf16x8*>(&As[buf][aoff[mi]]);
#pragma unroll
    for (int ni = 0; ni < 8; ++ni)
      bfr[ni] = *reinterpret_cast<const bf16x8*>(&Bs[buf][boff[ni]]);
#pragma unroll
    for (int mi = 0; mi < 4; ++mi)
#pragma unroll
      for (int ni = 0; ni < 8; ++ni)
        acc[mi][ni] = __builtin_amdgcn_mfma_f32_16x16x32_bf16(af[mi], bfr[ni],
                                                              acc[mi][ni], 0, 0, 0);
  };

  // ---- prologue: stage k-tile 0 into buffer 0
  {
    float4 v0, v1;
    loadA(0, v0, v1);
    stageB(0, 0);
    writeA(0, v0, v1);
  }
  __syncthreads();

  // ---- main loop: one barrier per k-step, double-buffered
#pragma unroll 2
  for (int kt = 0; kt < KSTEPS; ++kt) {
    const int cur = kt & 1, nxt = cur ^ 1;
    const bool more = (kt + 1 < KSTEPS);
    float4 v0, v1;
    if (more) {
      stageB(nxt, kt + 1);   // async global->LDS, drained by the barrier
      loadA(kt + 1, v0, v1); // global->regs, latency hidden under compute
    }
    compute(cur);
    if (more) writeA(nxt, v0, v1);
    __syncthreads();
  }

  // ---- fused epilogue: tanh + @W2 + b2
  float* red = reinterpret_cast<float*>(&As[0][0]);  // [128][4][3] = 6 KB, aliases As
#pragma unroll
  for (int mi = 0; mi < 4; ++mi) {
    float p[4][3] = {{0.f, 0.f, 0.f}, {0.f, 0.f, 0.f}, {0.f, 0.f, 0.f}, {0.f, 0.f, 0.f}};
#pragma unroll
    for (int ni = 0; ni < 8; ++ni) {
      int n = wnq * 128 + ni * 16 + lr;
      float bv = b1[n];
      float w0 = W2[n * 3 + 0], w1 = W2[n * 3 + 1], w2 = W2[n * 3 + 2];
#pragma unroll
      for (int r = 0; r < 4; ++r) {
        float h = tanh_fast(acc[mi][ni][r] + bv);
        p[r][0] += h * w0; p[r][1] += h * w1; p[r][2] += h * w2;
      }
    }
    // reduce across the 16 lanes holding this row's columns
#pragma unroll
    for (int m = 1; m < 16; m <<= 1) {
#pragma unroll
      for (int r = 0; r < 4; ++r)
#pragma unroll
        for (int o = 0; o < 3; ++o) p[r][o] += __shfl_xor(p[r][o], m, 64);
    }
    if (lr == 0) {
#pragma unroll
      for (int r = 0; r < 4; ++r) {
        int rowl = wm * 64 + mi * 16 + lq * 4 + r;
        red[rowl * 12 + wnq * 3 + 0] = p[r][0];
        red[rowl * 12 + wnq * 3 + 1] = p[r][1];
        red[rowl * 12 + wnq * 3 + 2] = p[r][2];
      }
    }
  }
  __syncthreads();
  if (t < BM * NOPS) {
    int r = t / 3, o = t - r * 3;
    float v = red[r * 12 + 0 + o] + red[r * 12 + 3 + o] +
              red[r * 12 + 6 + o] + red[r * 12 + 9 + o] + b2[o];
    out[(size_t)bid * (BM * NOPS) + t] = v;
  }
}

extern "C" void kernel_launch(void* const* d_in, const int* in_sizes, int n_in,
                              void* d_out, int out_size, void* d_ws, size_t ws_size,
                              hipStream_t stream) {
  const float* wenc    = (const float*)d_in[0];
  const float* rep_tab = (const float*)d_in[1];
  const float* W1      = (const float*)d_in[2];
  const float* b1      = (const float*)d_in[3];
  const float* W2      = (const float*)d_in[4];
  const float* b2      = (const float*)d_in[5];
  const int*   wn      = (const int*)d_in[6];
  const int*   wc      = (const int*)d_in[7];
  float*    outp = (float*)d_out;
  ushort_t* wsb  = (ushort_t*)d_ws;   // needs 1 MB; recomputed every launch

  prep_w1<<<256, 256, 0, stream>>>(W1, wsb);
  fused_main<<<NBLK, 512, 0, stream>>>(wenc, rep_tab, b1, W2, b2, wn, wc, wsb, outp);
}